// Round 6
// baseline (45.841 us; speedup 1.0000x reference)
//
#include <hip/hip_runtime.h>
#include <math.h>

#define NQ      100
#define BS      8
#define NC      4
#define NPTS    30
#define J_HALF  15          /* each lane of a pair owns 15 tgt points */
#define NTGT    512
#define P_TOTAL (NQ*BS)     /* 800 */
#define TILE_P  4           /* preds per block = waves per block */
#define TILE_T  32          /* tgts per block (per wave: 32 tgts x 2 lane-halves) */
#define NTHREADS 256

typedef float f32x2 __attribute__((ext_vector_type(2)));

// packed rotated sub: (a.s - b.s, a.r - b.r) in ONE v_pk_add_f32
__device__ __forceinline__ f32x2 pksub(f32x2 a, f32x2 b) {
    f32x2 r;
    asm("v_pk_add_f32 %0, %1, %2 neg_lo:[0,1] neg_hi:[0,1]"
        : "=v"(r) : "v"(a), "v"(b));
    return r;
}
// Chebyshev of rotated deltas == L1 of original: max(|ds|,|dr|) in ONE VOP3
__device__ __forceinline__ float maxabs2(f32x2 w) {
    float d;
    asm("v_max_f32 %0, abs(%1), abs(%2)" : "=v"(d) : "v"(w.x), "v"(w.y));
    return d;
}
__device__ __forceinline__ float min3f(float a, float b, float c) {
    float r;
    asm("v_min3_f32 %0, %1, %2, %3" : "=v"(r) : "v"(a), "v"(b), "v"(c));
    return r;
}

__global__ __launch_bounds__(NTHREADS) void matcher_kernel(
    const float* __restrict__ logits,      // [800,4]
    const float* __restrict__ pred_poly,   // [800,30,2]
    const int*   __restrict__ tgt_ids,     // [512]
    const float* __restrict__ tgt_poly,    // [512,30,2]
    float*       __restrict__ out)         // [800,512]
{
    // rotated coords: s = x+y, r = x-y  =>  L1 dist = max(|ds|, |dr|)
    __shared__ f32x2 srt_t[NPTS][TILE_T + 1];   // [j][t], padded
    __shared__ f32x2 srt_p[TILE_P][NPTS];
    __shared__ float prob_lds[TILE_P][NC];

    const int tid = threadIdx.x;
    const int p0  = blockIdx.x * TILE_P;
    const int t0  = blockIdx.y * TILE_T;

    // ---- stage 32 tgt polylines, rotate into (s,r) ----
    for (int idx = tid; idx < TILE_T * NPTS; idx += NTHREADS) {
        const int tt = idx / NPTS;
        const int j  = idx - tt * NPTS;
        const float2 v = *reinterpret_cast<const float2*>(
            tgt_poly + (size_t)(t0 + tt) * (NPTS * 2) + j * 2);
        srt_t[j][tt] = f32x2{v.x + v.y, v.x - v.y};
    }
    // ---- stage 4 pred polylines, rotate ----
    if (tid < TILE_P * NPTS) {
        const int pp = tid / NPTS;
        const int i  = tid - pp * NPTS;
        const float2 v = *reinterpret_cast<const float2*>(
            pred_poly + (size_t)(p0 + pp) * (NPTS * 2) + i * 2);
        srt_p[pp][i] = f32x2{v.x + v.y, v.x - v.y};
    }
    // ---- softmax over 4 classes ----
    if (tid < TILE_P) {
        const float* l = logits + (size_t)(p0 + tid) * NC;
        const float a0 = l[0], a1 = l[1], a2 = l[2], a3 = l[3];
        const float m  = fmaxf(fmaxf(a0, a1), fmaxf(a2, a3));
        const float e0 = expf(a0 - m), e1 = expf(a1 - m);
        const float e2 = expf(a2 - m), e3 = expf(a3 - m);
        const float inv = 1.0f / (e0 + e1 + e2 + e3);
        prob_lds[tid][0] = e0 * inv;
        prob_lds[tid][1] = e1 * inv;
        prob_lds[tid][2] = e2 * inv;
        prob_lds[tid][3] = e3 * inv;
    }
    __syncthreads();

    const int w     = tid >> 6;          // wave index = pred within tile
    const int lane  = tid & 63;
    const int tl    = lane >> 1;         // tgt within tile (0..31), shared by lane pair
    const int jbase = (lane & 1) * J_HALF;  // which 15 tgt points this lane owns

    // my HALF of the tgt polyline in registers: 15 x f32x2 = 30 VGPRs.
    // Live set (st 30 + m2 15 + temps ~15) fits the 64-VGPR/8-wave tier,
    // so the allocator has no remat incentive (R2-R4 lesson).
    f32x2 st[J_HALF];
#pragma unroll
    for (int k = 0; k < J_HALF; ++k) {
        st[k] = srt_t[jbase + k][tl];
        asm volatile("" : "+v"(st[k]));  // anti-sink pin
    }

    float m2[J_HALF];
#pragma unroll
    for (int k = 0; k < J_HALF; ++k) m2[k] = 1e30f;

    float sum1 = 0.0f;
#pragma unroll 1
    for (int i = 0; i < NPTS; i += 2) {
        const f32x2 pr0 = srt_p[w][i];       // wave-uniform broadcast
        const f32x2 pr1 = srt_p[w][i + 1];
        float dmin0 = 1e30f, dmin1 = 1e30f;
#pragma unroll
        for (int k = 0; k < J_HALF - 1; k += 2) {
            const float d0a = maxabs2(pksub(pr0, st[k]));
            const float d0b = maxabs2(pksub(pr0, st[k + 1]));
            const float d1a = maxabs2(pksub(pr1, st[k]));
            const float d1b = maxabs2(pksub(pr1, st[k + 1]));
            m2[k]     = min3f(m2[k],     d0a, d1a);
            m2[k + 1] = min3f(m2[k + 1], d0b, d1b);
            dmin0     = min3f(dmin0, d0a, d0b);
            dmin1     = min3f(dmin1, d1a, d1b);
        }
        {   // k = 14 tail
            const float d0 = maxabs2(pksub(pr0, st[J_HALF - 1]));
            const float d1 = maxabs2(pksub(pr1, st[J_HALF - 1]));
            m2[J_HALF - 1] = min3f(m2[J_HALF - 1], d0, d1);
            dmin0 = fminf(dmin0, d0);
            dmin1 = fminf(dmin1, d1);
        }
        // combine with partner lane (other 15 tgt points of the same t)
        dmin0 = fminf(dmin0, __shfl_xor(dmin0, 1, 64));
        dmin1 = fminf(dmin1, __shfl_xor(dmin1, 1, 64));
        sum1 += dmin0 + dmin1;
    }

    float sum2 = 0.0f;
#pragma unroll
    for (int k = 0; k < J_HALF; ++k) sum2 += m2[k];
    sum2 += __shfl_xor(sum2, 1, 64);

    if ((lane & 1) == 0) {
        const int   t   = t0 + tl;
        const int   cls = tgt_ids[t];
        const float cc  = -prob_lds[w][cls];
        out[(size_t)(p0 + w) * NTGT + t] = cc + (sum1 + sum2) * (0.5f / (float)NPTS);
    }
}

extern "C" void kernel_launch(void* const* d_in, const int* in_sizes, int n_in,
                              void* d_out, int out_size, void* d_ws, size_t ws_size,
                              hipStream_t stream) {
    const float* logits    = (const float*)d_in[0];
    const float* pred_poly = (const float*)d_in[1];
    const int*   tids      = (const int*)d_in[2];
    const float* tgt_poly  = (const float*)d_in[3];
    float*       out       = (float*)d_out;

    dim3 grid(P_TOTAL / TILE_P, NTGT / TILE_T);  // (200, 16)
    dim3 block(NTHREADS);
    matcher_kernel<<<grid, block, 0, stream>>>(logits, pred_poly, tids, tgt_poly, out);
}